// Round 3
// baseline (96.889 us; speedup 1.0000x reference)
//
#include <hip/hip_runtime.h>

#define NQ 14
#define DIM 16384
#define OUT_N 1000

using v2f = __attribute__((ext_vector_type(2))) float;

__host__ __device__ constexpr int WI(int l, int i, int k) {
    return 14 + (l * 13 + i) * 2 + k;  // weights[l,i,k] slot after 14 bias slots
}

// LDS xor-swizzles (bijective; all access patterns <=2-way bank aliased = free)
__device__ __forceinline__ int swzM(int e) { return e ^ ((e >> 6) & 31); }  // 16384-space
__device__ __forceinline__ int swzB(int a) { return a ^ ((a >> 5) & 31); }  // 2048-space

// RY on element-bit B of a tile of NP float2 pairs. B>=1 -> packed fp32.
template<int B, int NP>
__device__ __forceinline__ void ry(v2f* x, float c, float s) {
    if constexpr (B == 0) {
#pragma unroll
        for (int p = 0; p < NP; ++p) {
            float a0 = x[p].x, a1 = x[p].y;
            x[p].x = c * a0 - s * a1;
            x[p].y = s * a0 + c * a1;
        }
    } else {
        constexpr int pb = B - 1;
#pragma unroll
        for (int m = 0; m < NP / 2; ++m) {
            int p0 = ((m >> pb) << (pb + 1)) | (m & ((1 << pb) - 1));
            int p1 = p0 | (1 << pb);
            v2f lo = x[p0], hi = x[p1];
            x[p0] = lo * c - hi * s;
            x[p1] = hi * c + lo * s;
        }
    }
}

// CZ: negate elements with element-bits BH and BL both set.
template<int BH, int BL, int NP>
__device__ __forceinline__ void cz(v2f* x) {
    static_assert(BH > BL, "");
    if constexpr (BL >= 1) {
#pragma unroll
        for (int p = 0; p < NP; ++p)
            if (((p >> (BH - 1)) & 1) && ((p >> (BL - 1)) & 1)) x[p] = -x[p];
    } else {
#pragma unroll
        for (int p = 0; p < NP; ++p)
            if ((p >> (BH - 1)) & 1) x[p].y = -x[p].y;
    }
}

#define BLK(BH, I0, I1, NP)                                       \
    cz<BH, BH - 1, NP>(x);                                        \
    { float2 cc = csl[I0]; ry<BH, NP>(x, cc.x, cc.y); }           \
    { float2 cd = csl[I1]; ry<BH - 1, NP>(x, cd.x, cd.y); }

// ---------------------------------------------------------------------------
// Gate schedule (qubit w <-> element bit 13-w; full dep-DAG check in session):
//  W-M  (regs=e5..0=q8..13, layout e=t<<6|r): I8..I13; B(0,8) B(0,10) B(0,12)
//       B(0,9) B(0,11) B(1,10) B(1,12) B(1,11)
//  [64KB LDS transpose]
//  W-S1 (regs=e13..8=q0..5, layout e=r<<8|t): I0..I5; B(0,0) B(0,2) B(0,4)
//       B(0,1) B(0,3) B(1,0) B(1,2) B(1,1)
//  [prune: q0,q1,q2 complete -> keep e13..11=111, a=e-14336, 2048 amps in 8KB LDS]
//  wave0 only, 32 amps/thread:
//  W-B1 (regs=a10..6=q3..7, a=l<<6|s):  I6 I7; B(0,6) B(0,5) B(1,4) B(1,3)
//  W-B2 (regs=a8..4=q5..9):             B(0,7) B(1,6) B(1,8) B(1,5) B(1,7)
//  W-B3 (regs=a6..2=q7..11):            B(1,9)   -> output a in [1048,2048)
// Deps verified: every B(0,odd) after its even neighbors; every B(1,even i)
// after B(0,i-1..i+1); every B(1,odd) after B(1,even) neighbors; inits first.
// ---------------------------------------------------------------------------
__global__ __launch_bounds__(256, 2)
void qnn_fused(const float* __restrict__ in, const float* __restrict__ wts,
               const float* __restrict__ bias, float* __restrict__ out) {
    __shared__ float lds[DIM];     // 64 KB state; first 8 KB reused for pruned phase
    __shared__ float2 csl[66];
    __shared__ float red[4];

    const int t = threadIdx.x;
    const int b = blockIdx.x;

    // per-block cos/sin of the 66 angles (replaces a separate launch)
    if (t < 66) {
        float th = (t < NQ) ? bias[t] : wts[t - NQ];
        csl[t] = make_float2(cosf(0.5f * th), sinf(0.5f * th));
    }

    // ---- load: layout M, e = t<<6 | r  (thread-contiguous -> float4 loads)
    v2f x[32];
    { const float4* __restrict__ src4 = (const float4*)(in + (size_t)b * DIM + t * 64);
#pragma unroll
      for (int i = 0; i < 16; ++i) {
          float4 f = src4[i];
          x[2 * i].x = f.x;     x[2 * i].y = f.y;
          x[2 * i + 1].x = f.z; x[2 * i + 1].y = f.w;
      } }

    // ---- sum of squares -> scale (norm folded into pruned amplitudes)
    float pp = 0.f;
#pragma unroll
    for (int p = 0; p < 32; ++p) pp = fmaf(x[p].x, x[p].x, fmaf(x[p].y, x[p].y, pp));
#pragma unroll
    for (int d = 32; d; d >>= 1) pp += __shfl_xor(pp, d);
    if ((t & 63) == 0) red[t >> 6] = pp;
    __syncthreads();                       // also publishes csl
    const float scale = 1.0f / sqrtf(red[0] + red[1] + red[2] + red[3]);

    // ---- W-M: q8->bit5 ... q13->bit0
    { float2 cc;
      cc = csl[8];  ry<5, 32>(x, cc.x, cc.y);
      cc = csl[9];  ry<4, 32>(x, cc.x, cc.y);
      cc = csl[10]; ry<3, 32>(x, cc.x, cc.y);
      cc = csl[11]; ry<2, 32>(x, cc.x, cc.y);
      cc = csl[12]; ry<1, 32>(x, cc.x, cc.y);
      cc = csl[13]; ry<0, 32>(x, cc.x, cc.y); }
    BLK(5, WI(0,8,0),  WI(0,8,1),  32)   // B(0,8):  q8,q9
    BLK(3, WI(0,10,0), WI(0,10,1), 32)   // B(0,10): q10,q11
    BLK(1, WI(0,12,0), WI(0,12,1), 32)   // B(0,12): q12,q13
    BLK(4, WI(0,9,0),  WI(0,9,1),  32)   // B(0,9):  q9,q10
    BLK(2, WI(0,11,0), WI(0,11,1), 32)   // B(0,11): q11,q12
    BLK(3, WI(1,10,0), WI(1,10,1), 32)   // B(1,10): q10,q11
    BLK(1, WI(1,12,0), WI(1,12,1), 32)   // B(1,12): q12,q13
    BLK(2, WI(1,11,0), WI(1,11,1), 32)   // B(1,11): q11,q12

    // ---- transpose M -> S1 through 64 KB LDS (swizzled, 2-way free)
#pragma unroll
    for (int r = 0; r < 64; ++r)
        lds[swzM((t << 6) | r)] = (r & 1) ? x[r >> 1].y : x[r >> 1].x;
    __syncthreads();
#pragma unroll
    for (int r = 0; r < 64; ++r) {
        float v = lds[swzM((r << 8) | t)];
        if (r & 1) x[r >> 1].y = v; else x[r >> 1].x = v;
    }

    // ---- W-S1: q0->bit5 ... q5->bit0
    { float2 cc;
      cc = csl[0]; ry<5, 32>(x, cc.x, cc.y);
      cc = csl[1]; ry<4, 32>(x, cc.x, cc.y);
      cc = csl[2]; ry<3, 32>(x, cc.x, cc.y);
      cc = csl[3]; ry<2, 32>(x, cc.x, cc.y);
      cc = csl[4]; ry<1, 32>(x, cc.x, cc.y);
      cc = csl[5]; ry<0, 32>(x, cc.x, cc.y); }
    BLK(5, WI(0,0,0), WI(0,0,1), 32)   // B(0,0): q0,q1
    BLK(3, WI(0,2,0), WI(0,2,1), 32)   // B(0,2): q2,q3
    BLK(1, WI(0,4,0), WI(0,4,1), 32)   // B(0,4): q4,q5
    BLK(4, WI(0,1,0), WI(0,1,1), 32)   // B(0,1): q1,q2
    BLK(2, WI(0,3,0), WI(0,3,1), 32)   // B(0,3): q3,q4
    BLK(5, WI(1,0,0), WI(1,0,1), 32)   // B(1,0): q0,q1
    BLK(3, WI(1,2,0), WI(1,2,1), 32)   // B(1,2): q2,q3
    BLK(4, WI(1,1,0), WI(1,1,1), 32)   // B(1,1): q1,q2

    // ---- prune: keep r in [56,64) -> a = (r-56)<<8 | t, scaled, into 8 KB LDS
    __syncthreads();   // all transpose reads done before overwriting lds[0..2048)
#pragma unroll
    for (int p = 28; p < 32; ++p) {
        lds[swzB(((2 * p - 56) << 8) | t)] = x[p].x * scale;
        lds[swzB(((2 * p - 55) << 8) | t)] = x[p].y * scale;
    }
    __syncthreads();

    // ---- wave 0 finishes the pruned 2048-amp state (32 amps/thread)
    if (t < 64) {
        const int s = t;
#pragma unroll
        for (int l = 0; l < 32; ++l) {           // gather L-B1: a = l<<6 | s
            float v = lds[swzB((l << 6) | s)];
            if (l & 1) x[l >> 1].y = v; else x[l >> 1].x = v;
        }
        // W-B1: q3->4 q4->3 q5->2 q6->1 q7->0
        { float2 cc;
          cc = csl[6]; ry<1, 16>(x, cc.x, cc.y);
          cc = csl[7]; ry<0, 16>(x, cc.x, cc.y); }
        BLK(1, WI(0,6,0), WI(0,6,1), 16)   // B(0,6): q6,q7
        BLK(2, WI(0,5,0), WI(0,5,1), 16)   // B(0,5): q5,q6
        BLK(3, WI(1,4,0), WI(1,4,1), 16)   // B(1,4): q4,q5
        BLK(4, WI(1,3,0), WI(1,3,1), 16)   // B(1,3): q3,q4
#pragma unroll
        for (int l = 0; l < 32; ++l)             // X1 write (same addrs as gather)
            lds[swzB((l << 6) | s)] = (l & 1) ? x[l >> 1].y : x[l >> 1].x;
    }
    __syncthreads();
    if (t < 64) {
        const int s = t;
#pragma unroll
        for (int l = 0; l < 32; ++l) {           // read L-B2: a = s[5:4]<<9|l<<4|s[3:0]
            float v = lds[swzB(((s >> 4) << 9) | (l << 4) | (s & 15))];
            if (l & 1) x[l >> 1].y = v; else x[l >> 1].x = v;
        }
        // W-B2: q5->4 q6->3 q7->2 q8->1 q9->0
        BLK(2, WI(0,7,0), WI(0,7,1), 16)   // B(0,7): q7,q8
        BLK(3, WI(1,6,0), WI(1,6,1), 16)   // B(1,6): q6,q7
        BLK(1, WI(1,8,0), WI(1,8,1), 16)   // B(1,8): q8,q9
        BLK(4, WI(1,5,0), WI(1,5,1), 16)   // B(1,5): q5,q6
        BLK(2, WI(1,7,0), WI(1,7,1), 16)   // B(1,7): q7,q8
#pragma unroll
        for (int l = 0; l < 32; ++l)             // X2 write (same addrs)
            lds[swzB(((s >> 4) << 9) | (l << 4) | (s & 15))] =
                (l & 1) ? x[l >> 1].y : x[l >> 1].x;
    }
    __syncthreads();
    if (t < 64) {
        const int s = t;
#pragma unroll
        for (int l = 0; l < 32; ++l) {           // read L-B3: a = s[5:2]<<7|l<<2|s[1:0]
            float v = lds[swzB(((s >> 2) << 7) | (l << 2) | (s & 3))];
            if (l & 1) x[l >> 1].y = v; else x[l >> 1].x = v;
        }
        // W-B3: q7->4 q8->3 q9->2 q10->1 q11->0
        BLK(2, WI(1,9,0), WI(1,9,1), 16)   // B(1,9): q9,q10

        // output: e = 14336 + a, j = a - 1048; a>=1024 only for s>=32
        if (s >= 32) {
            float* __restrict__ orow = out + (size_t)b * OUT_N;
            const int base = ((s >> 2) << 7) | (s & 3);
#pragma unroll
            for (int l = 0; l < 32; ++l) {
                int j = base + (l << 2) - 1048;
                float v = (l & 1) ? x[l >> 1].y : x[l >> 1].x;
                if (j >= 0) orow[j] = v * v;
            }
        }
    }
}

extern "C" void kernel_launch(void* const* d_in, const int* in_sizes, int n_in,
                              void* d_out, int out_size, void* d_ws, size_t ws_size,
                              hipStream_t stream) {
    const float* in   = (const float*)d_in[0];
    const float* wts  = (const float*)d_in[1];
    const float* bias = (const float*)d_in[2];
    float* out = (float*)d_out;

    const int nb = in_sizes[0] / DIM;   // 512 batch rows
    qnn_fused<<<nb, 256, 0, stream>>>(in, wts, bias, out);
}

// Round 4
// 90.653 us; speedup vs baseline: 1.0688x; 1.0688x over previous
//
#include <hip/hip_runtime.h>

#define NQ 14
#define DIM 16384
#define OUT_N 1000
#define PRUNED 2048   // amps kept after S1 (e bits 13..11 == 111)

using v2f = __attribute__((ext_vector_type(2))) float;

__host__ __device__ constexpr int WI(int l, int i, int k) {
    return 14 + (l * 13 + i) * 2 + k;  // weights[l,i,k] slot after 14 bias slots
}

// LDS xor-swizzle for the 2048-float buffer: every access pattern used below
// is <=2-way bank aliased (free per m136).
__device__ __forceinline__ int swzB(int a) { return a ^ ((a >> 5) & 31); }

// RY on element-bit B of a tile of NP float2 pairs. B>=1 -> packed fp32.
template<int B, int NP>
__device__ __forceinline__ void ry(v2f* x, float c, float s) {
    if constexpr (B == 0) {
#pragma unroll
        for (int p = 0; p < NP; ++p) {
            float a0 = x[p].x, a1 = x[p].y;
            x[p].x = c * a0 - s * a1;
            x[p].y = s * a0 + c * a1;
        }
    } else {
        constexpr int pb = B - 1;
#pragma unroll
        for (int m = 0; m < NP / 2; ++m) {
            int p0 = ((m >> pb) << (pb + 1)) | (m & ((1 << pb) - 1));
            int p1 = p0 | (1 << pb);
            v2f lo = x[p0], hi = x[p1];
            x[p0] = lo * c - hi * s;
            x[p1] = hi * c + lo * s;
        }
    }
}

// CZ: negate elements with element-bits BH and BL both set.
template<int BH, int BL, int NP>
__device__ __forceinline__ void cz(v2f* x) {
    static_assert(BH > BL, "");
    if constexpr (BL >= 1) {
#pragma unroll
        for (int p = 0; p < NP; ++p)
            if (((p >> (BH - 1)) & 1) && ((p >> (BL - 1)) & 1)) x[p] = -x[p];
    } else {
#pragma unroll
        for (int p = 0; p < NP; ++p)
            if ((p >> (BH - 1)) & 1) x[p].y = -x[p].y;
    }
}

#define BLK(BH, I0, I1, NP)                                       \
    cz<BH, BH - 1, NP>(x);                                        \
    { float2 cc = csl[I0]; ry<BH, NP>(x, cc.x, cc.y); }           \
    { float2 cd = csl[I1]; ry<BH - 1, NP>(x, cd.x, cd.y); }

// ---------------------------------------------------------------------------
// Schedule (qubit w <-> element bit 13-w of e; dep-DAG verified, and this
// exact split/ordering passed end-to-end in round 2 at absmax 1.9e-6):
//  S1 (full state, regs = e13..8 = q0..5, layout e=l<<8|t):
//      I0..I5; B(0,0) B(0,2) B(0,4) B(0,1) B(0,3) B(1,0) B(1,2) B(1,1)
//    -> every gate on q0,q1,q2 complete: keep e13..11=111, a = e-14336.
//  Tail (2048 amps, wave 0, 32/thread; a bit 13-w holds qubit w):
//   U1 (L1: a=s<<5|l,              regs a4..0 = q9..13): I9..I13;
//       B(0,10) B(0,12) B(0,11) B(1,12)
//   U2 (L2: a=(s>>4)<<9|l<<4|s&15, regs a8..4 = q5..9):  I6 I7 I8;
//       B(0,6) B(0,8) B(0,5) B(0,7) B(1,6)
//   U3 (L3: a=(s>>2)<<7|l<<2|s&3,  regs a6..2 = q7..11):
//       B(0,9) B(1,8) B(1,10) B(1,7) B(1,9)
//   U4 (L4: a=l<<6|s,              regs a10..6 = q3..7):
//       B(1,4) B(1,3) B(1,5)
//   U5 (L1):  B(1,11)   -> output a in [1048,2048)
// ---------------------------------------------------------------------------
__global__ __launch_bounds__(256, 2)
void qnn_fused2(const float* __restrict__ in, const float* __restrict__ wts,
                const float* __restrict__ bias, float* __restrict__ out) {
    __shared__ float lds[PRUNED];     // 8 KB swizzled pruned-state buffer
    __shared__ float2 csl[66];
    __shared__ float red[4];

    const int t = threadIdx.x;
    const int b = blockIdx.x;

    // per-block cos/sin of the 66 angles
    if (t < 66) {
        float th = (t < NQ) ? bias[t] : wts[t - NQ];
        csl[t] = make_float2(cosf(0.5f * th), sinf(0.5f * th));
    }

    // ---- load, layout e = l<<8 | t: per-wave fully coalesced dword loads
    const float* __restrict__ xin = in + (size_t)b * DIM;
    v2f x[32];
#pragma unroll
    for (int p = 0; p < 32; ++p) {
        x[p].x = xin[((2 * p) << 8) | t];
        x[p].y = xin[((2 * p + 1) << 8) | t];
    }

    // ---- sum of squares -> scale (normalization folded into pruned amps)
    float pp = 0.f;
#pragma unroll
    for (int p = 0; p < 32; ++p) pp = fmaf(x[p].x, x[p].x, fmaf(x[p].y, x[p].y, pp));
#pragma unroll
    for (int d = 32; d; d >>= 1) pp += __shfl_xor(pp, d);
    if ((t & 63) == 0) red[t >> 6] = pp;
    __syncthreads();                      // also publishes csl
    const float scale = 1.0f / sqrtf(red[0] + red[1] + red[2] + red[3]);

    // ---- S1: q0->bit5 ... q5->bit0 of l
    { float2 cc;
      cc = csl[0]; ry<5, 32>(x, cc.x, cc.y);
      cc = csl[1]; ry<4, 32>(x, cc.x, cc.y);
      cc = csl[2]; ry<3, 32>(x, cc.x, cc.y);
      cc = csl[3]; ry<2, 32>(x, cc.x, cc.y);
      cc = csl[4]; ry<1, 32>(x, cc.x, cc.y);
      cc = csl[5]; ry<0, 32>(x, cc.x, cc.y); }
    BLK(5, WI(0,0,0), WI(0,0,1), 32)   // B(0,0): q0,q1
    BLK(3, WI(0,2,0), WI(0,2,1), 32)   // B(0,2): q2,q3
    BLK(1, WI(0,4,0), WI(0,4,1), 32)   // B(0,4): q4,q5
    BLK(4, WI(0,1,0), WI(0,1,1), 32)   // B(0,1): q1,q2
    BLK(2, WI(0,3,0), WI(0,3,1), 32)   // B(0,3): q3,q4
    BLK(5, WI(1,0,0), WI(1,0,1), 32)   // B(1,0): q0,q1
    BLK(3, WI(1,2,0), WI(1,2,1), 32)   // B(1,2): q2,q3
    BLK(4, WI(1,1,0), WI(1,1,1), 32)   // B(1,1): q1,q2

    // ---- prune: keep l in [56,64) -> a = (l-56)<<8 | t, scaled, into LDS
#pragma unroll
    for (int p = 28; p < 32; ++p) {
        lds[swzB(((2 * p - 56) << 8) | t)] = x[p].x * scale;
        lds[swzB(((2 * p - 55) << 8) | t)] = x[p].y * scale;
    }
    __syncthreads();

    // ---- wave 0 finishes the pruned 2048-amp state (32 amps/thread)
    if (t < 64) {
        const int s = t;
#pragma unroll
        for (int l = 0; l < 32; ++l) {           // gather L1: a = s<<5 | l
            float v = lds[swzB((s << 5) | l)];
            if (l & 1) x[l >> 1].y = v; else x[l >> 1].x = v;
        }
        // U1: q9->4 q10->3 q11->2 q12->1 q13->0
        { float2 cc;
          cc = csl[9];  ry<4, 16>(x, cc.x, cc.y);
          cc = csl[10]; ry<3, 16>(x, cc.x, cc.y);
          cc = csl[11]; ry<2, 16>(x, cc.x, cc.y);
          cc = csl[12]; ry<1, 16>(x, cc.x, cc.y);
          cc = csl[13]; ry<0, 16>(x, cc.x, cc.y); }
        BLK(3, WI(0,10,0), WI(0,10,1), 16)   // B(0,10): q10,q11
        BLK(1, WI(0,12,0), WI(0,12,1), 16)   // B(0,12): q12,q13
        BLK(2, WI(0,11,0), WI(0,11,1), 16)   // B(0,11): q11,q12
        BLK(1, WI(1,12,0), WI(1,12,1), 16)   // B(1,12): q12,q13
#pragma unroll
        for (int l = 0; l < 32; ++l)             // X1 write L1
            lds[swzB((s << 5) | l)] = (l & 1) ? x[l >> 1].y : x[l >> 1].x;
    }
    __syncthreads();
    if (t < 64) {
        const int s = t;
#pragma unroll
        for (int l = 0; l < 32; ++l) {           // read L2
            float v = lds[swzB(((s >> 4) << 9) | (l << 4) | (s & 15))];
            if (l & 1) x[l >> 1].y = v; else x[l >> 1].x = v;
        }
        // U2: q5->4 q6->3 q7->2 q8->1 q9->0
        { float2 cc;
          cc = csl[6]; ry<3, 16>(x, cc.x, cc.y);
          cc = csl[7]; ry<2, 16>(x, cc.x, cc.y);
          cc = csl[8]; ry<1, 16>(x, cc.x, cc.y); }
        BLK(3, WI(0,6,0), WI(0,6,1), 16)   // B(0,6): q6,q7
        BLK(1, WI(0,8,0), WI(0,8,1), 16)   // B(0,8): q8,q9
        BLK(4, WI(0,5,0), WI(0,5,1), 16)   // B(0,5): q5,q6
        BLK(2, WI(0,7,0), WI(0,7,1), 16)   // B(0,7): q7,q8
        BLK(3, WI(1,6,0), WI(1,6,1), 16)   // B(1,6): q6,q7
#pragma unroll
        for (int l = 0; l < 32; ++l)             // X2 write L2
            lds[swzB(((s >> 4) << 9) | (l << 4) | (s & 15))] =
                (l & 1) ? x[l >> 1].y : x[l >> 1].x;
    }
    __syncthreads();
    if (t < 64) {
        const int s = t;
#pragma unroll
        for (int l = 0; l < 32; ++l) {           // read L3
            float v = lds[swzB(((s >> 2) << 7) | (l << 2) | (s & 3))];
            if (l & 1) x[l >> 1].y = v; else x[l >> 1].x = v;
        }
        // U3: q7->4 q8->3 q9->2 q10->1 q11->0
        BLK(2, WI(0,9,0),  WI(0,9,1),  16)   // B(0,9):  q9,q10
        BLK(3, WI(1,8,0),  WI(1,8,1),  16)   // B(1,8):  q8,q9
        BLK(1, WI(1,10,0), WI(1,10,1), 16)   // B(1,10): q10,q11
        BLK(4, WI(1,7,0),  WI(1,7,1),  16)   // B(1,7):  q7,q8
        BLK(2, WI(1,9,0),  WI(1,9,1),  16)   // B(1,9):  q9,q10
#pragma unroll
        for (int l = 0; l < 32; ++l)             // X3 write L3
            lds[swzB(((s >> 2) << 7) | (l << 2) | (s & 3))] =
                (l & 1) ? x[l >> 1].y : x[l >> 1].x;
    }
    __syncthreads();
    if (t < 64) {
        const int s = t;
#pragma unroll
        for (int l = 0; l < 32; ++l) {           // read L4: a = l<<6 | s
            float v = lds[swzB((l << 6) | s)];
            if (l & 1) x[l >> 1].y = v; else x[l >> 1].x = v;
        }
        // U4: q3->4 q4->3 q5->2 q6->1 q7->0
        BLK(3, WI(1,4,0), WI(1,4,1), 16)   // B(1,4): q4,q5
        BLK(4, WI(1,3,0), WI(1,3,1), 16)   // B(1,3): q3,q4
        BLK(2, WI(1,5,0), WI(1,5,1), 16)   // B(1,5): q5,q6
#pragma unroll
        for (int l = 0; l < 32; ++l)             // X4 write L4
            lds[swzB((l << 6) | s)] = (l & 1) ? x[l >> 1].y : x[l >> 1].x;
    }
    __syncthreads();
    if (t < 64) {
        const int s = t;
#pragma unroll
        for (int l = 0; l < 32; ++l) {           // read L1
            float v = lds[swzB((s << 5) | l)];
            if (l & 1) x[l >> 1].y = v; else x[l >> 1].x = v;
        }
        // U5: B(1,11): q11->2, q12->1
        BLK(2, WI(1,11,0), WI(1,11,1), 16)

        // output: e = 14336 + a, j = a - 1048 for a = s*32 + l in [1048,2048)
        if (s >= 32) {
            float* __restrict__ orow = out + (size_t)b * OUT_N;
            const int base = s * 32 - 1048;
#pragma unroll
            for (int l = 0; l < 32; ++l) {
                int j = base + l;
                float v = (l & 1) ? x[l >> 1].y : x[l >> 1].x;
                if (j >= 0) orow[j] = v * v;
            }
        }
    }
}

extern "C" void kernel_launch(void* const* d_in, const int* in_sizes, int n_in,
                              void* d_out, int out_size, void* d_ws, size_t ws_size,
                              hipStream_t stream) {
    const float* in   = (const float*)d_in[0];
    const float* wts  = (const float*)d_in[1];
    const float* bias = (const float*)d_in[2];
    float* out = (float*)d_out;

    const int nb = in_sizes[0] / DIM;   // 512 batch rows
    qnn_fused2<<<nb, 256, 0, stream>>>(in, wts, bias, out);
}